// Round 8
// baseline (330.687 us; speedup 1.0000x reference)
//
#include <hip/hip_runtime.h>
#include <stdint.h>

#define N_ROWS 16384
#define M_ROWS 16384
#define KDIM   512
#define BM 64            // 1 wave x 64 rows per block
#define BNT 64           // cols per bt tile
#define BKP 128          // k per phase (one MFMA K)
#define NCHUNK 8
#define CHUNK_ROWS (M_ROWS / NCHUNK)       // 2048
#define BT_PER_CHUNK (CHUNK_ROWS / BNT)    // 32

typedef int intx4 __attribute__((ext_vector_type(4)));
typedef int intx8 __attribute__((ext_vector_type(8)));
typedef float floatx4 __attribute__((ext_vector_type(4)));

#define UNIT_SCALE 0x7F7F7F7F  // E8M0 exponent 127 -> 2^0 = 1.0 in every byte

// Kernel 1: fp32 -> fp8 e4m3 (unit scale) + per-row squared norms (fp32).
// One wave per row; 16 waves/block.
__global__ void __launch_bounds__(1024)
conv_kernel(const float* __restrict__ A, const float* __restrict__ B,
            uint8_t* __restrict__ Ah8, uint8_t* __restrict__ Bh8,
            float* __restrict__ sq1, float* __restrict__ sq2) {
  const int lane = threadIdx.x & 63;
  const int wv = threadIdx.x >> 6;
  int row = blockIdx.x * 16 + wv;
  const float* src;
  uint8_t* dst;
  float* sq;
  if (row < N_ROWS) {
    src = A + (size_t)row * KDIM;
    dst = Ah8 + (size_t)row * KDIM;
    sq = sq1 + row;
  } else {
    int r = row - N_ROWS;
    src = B + (size_t)r * KDIM;
    dst = Bh8 + (size_t)r * KDIM;
    sq = sq2 + r;
  }
  const float4* s4 = (const float4*)src;
  float4 v0 = s4[lane * 2];
  float4 v1 = s4[lane * 2 + 1];
  uint32_t w0 = 0, w1 = 0;
  w0 = __builtin_amdgcn_cvt_pk_fp8_f32(v0.x, v0.y, w0, 0);
  w0 = __builtin_amdgcn_cvt_pk_fp8_f32(v0.z, v0.w, w0, 1);
  w1 = __builtin_amdgcn_cvt_pk_fp8_f32(v1.x, v1.y, w1, 0);
  w1 = __builtin_amdgcn_cvt_pk_fp8_f32(v1.z, v1.w, w1, 1);
  uint2 pk = {w0, w1};
  ((uint2*)dst)[lane] = pk;
  float s = v0.x * v0.x + v0.y * v0.y + v0.z * v0.z + v0.w * v0.w
          + v1.x * v1.x + v1.y * v1.y + v1.z * v1.z + v1.w * v1.w;
  #pragma unroll
  for (int off = 32; off; off >>= 1) s += __shfl_down(s, off, 64);
  if (lane == 0) *sq = s;
}

// Kernel 2: fused fp8 GEMM + running-min — NO LDS, NO BARRIERS.
// R7 post-mortem: LDS pipe (reads at the 12-cyc b128 floor + DMA writes)
// costs ~163k cyc/CU vs the 141k MFMA floor and can't overlap away; since
// 1-wave blocks share nothing, LDS was a pure staging bounce. Here each
// wave loads its B fragments straight global->VGPR (L2-resident 1MB chunk,
// XCD-pinned via chunk = bid & 7); the VMEM queue + compiler vmcnt waits
// software-pipeline the stream under the MFMAs (AITER-style K-loop: no
// barrier, no vmcnt(0) drain). A stays register-persistent: areg[4][4]
// intx8 = 128 arch VGPRs; acc 64 on the AGPR side; 2 waves/SIMD.
__global__ void __launch_bounds__(64, 2)
gemm_min_kernel(const uint8_t* __restrict__ Ah8, const uint8_t* __restrict__ Bh8,
                const float* __restrict__ sq2, float* __restrict__ ws_min) {
  const int lane = threadIdx.x;  // 0..63
  const int fr = lane & 15;
  const int kg = lane >> 4;      // 0..3

  const int bid = blockIdx.x;
  const int chunk = bid & 7;     // == XCD under bid%8 round-robin
  const int rowBase = (bid >> 3) * BM;
  const int colBase0 = chunk * CHUNK_ROWS;

  // ---- Persistent A fragments: areg[i][p] = row (rowBase + i*16 + fr),
  // k = p*128 + kg*32 .. +32.
  intx8 areg[4][4];
  {
    const uint8_t* abase = Ah8 + (size_t)(rowBase + fr) * KDIM + kg * 32;
    #pragma unroll
    for (int i = 0; i < 4; i++)
      #pragma unroll
      for (int p = 0; p < 4; p++) {
        const uint8_t* ap = abase + (size_t)i * 16 * KDIM + p * BKP;
        intx4 lo = *(const intx4*)ap;
        intx4 hi = *(const intx4*)(ap + 16);
        areg[i][p] = __builtin_shufflevector(lo, hi, 0, 1, 2, 3, 4, 5, 6, 7);
      }
  }

  float runmin[4][4];
  #pragma unroll
  for (int i = 0; i < 4; i++)
    #pragma unroll
    for (int r4 = 0; r4 < 4; r4++) runmin[i][r4] = 3.0e38f;

  for (int bt = 0; bt < BT_PER_CHUNK; ++bt) {
    const int colBase = colBase0 + bt * BNT;
    // Per-lane B base for this tile: col = colBase + fr (+ j*16 via imm-free
    // pointer adds), byte = col*KDIM + p*128 + kg*32 (+0/16) — p,j offsets
    // are compile-time constants in the unrolled loop.
    const uint8_t* bbase = Bh8 + (size_t)(colBase + fr) * KDIM + kg * 32;

    floatx4 acc[4][4];
    #pragma unroll
    for (int i = 0; i < 4; i++)
      #pragma unroll
      for (int j = 0; j < 4; j++) acc[i][j] = (floatx4){0.f, 0.f, 0.f, 0.f};

    #pragma unroll
    for (int p = 0; p < 4; ++p) {
      #pragma unroll
      for (int j = 0; j < 4; j++) {
        const uint8_t* bp = bbase + (size_t)j * (16 * KDIM) + p * BKP;
        intx4 lo = *(const intx4*)bp;          // k = p*128 + kg*32 .. +16
        intx4 hi = *(const intx4*)(bp + 16);   // k = .. +16 .. +32
        intx8 bv = __builtin_shufflevector(lo, hi, 0, 1, 2, 3, 4, 5, 6, 7);
        #pragma unroll
        for (int i = 0; i < 4; i++)
          acc[i][j] = __builtin_amdgcn_mfma_scale_f32_16x16x128_f8f6f4(
              areg[i][p], bv, acc[i][j], 0, 0,
              0, UNIT_SCALE, 0, UNIT_SCALE);
      }
    }

    // Epilogue: cand = sq2[col] - 2*inner -> per-row running min.
    #pragma unroll
    for (int j = 0; j < 4; j++) {
      const float s2 = sq2[colBase + j * 16 + fr];
      #pragma unroll
      for (int i = 0; i < 4; i++)
        #pragma unroll
        for (int r4 = 0; r4 < 4; r4++) {
          const float cand = fmaf(-2.f, acc[i][j][r4], s2);
          runmin[i][r4] = fminf(runmin[i][r4], cand);
        }
    }
  }

  // Min over the 16 columns per lane row-group: butterfly on lane bits 0..3.
  #pragma unroll
  for (int i = 0; i < 4; i++)
    #pragma unroll
    for (int r4 = 0; r4 < 4; r4++) {
      float v = runmin[i][r4];
      v = fminf(v, __shfl_xor(v, 1, 64));
      v = fminf(v, __shfl_xor(v, 2, 64));
      v = fminf(v, __shfl_xor(v, 4, 64));
      v = fminf(v, __shfl_xor(v, 8, 64));
      runmin[i][r4] = v;
    }

  if (fr == 0) {
    #pragma unroll
    for (int i = 0; i < 4; i++)
      #pragma unroll
      for (int r4 = 0; r4 < 4; r4++) {
        const int lrow = i * 16 + kg * 4 + r4;
        ws_min[(size_t)chunk * N_ROWS + rowBase + lrow] = runmin[i][r4];
      }
  }
}

// Kernel 3a: per-row min across chunks + sqrt/relu, 64-block partial sums.
__global__ void partial_kernel(const float* __restrict__ ws_min,
                               const float* __restrict__ sq1,
                               float* __restrict__ part) {
  const int r = blockIdx.x * 256 + threadIdx.x;
  float m = ws_min[r];
  #pragma unroll
  for (int c = 1; c < NCHUNK; c++) m = fminf(m, ws_min[(size_t)c * N_ROWS + r]);
  float d2 = sq1[r] + m;
  d2 = d2 > 0.f ? d2 : 0.f;
  float v = sqrtf(d2) - 0.1f;
  float s = v > 0.f ? v : 0.f;
  #pragma unroll
  for (int off = 32; off; off >>= 1) s += __shfl_down(s, off, 64);
  __shared__ float ps[4];
  if ((threadIdx.x & 63) == 0) ps[threadIdx.x >> 6] = s;
  __syncthreads();
  if (threadIdx.x == 0) part[blockIdx.x] = ps[0] + ps[1] + ps[2] + ps[3];
}

// Kernel 3b: combine 64 partials.
__global__ void final_kernel(const float* __restrict__ part, float* __restrict__ out) {
  float s = part[threadIdx.x];
  #pragma unroll
  for (int off = 32; off; off >>= 1) s += __shfl_down(s, off, 64);
  if (threadIdx.x == 0) out[0] = s / (float)N_ROWS;
}

extern "C" void kernel_launch(void* const* d_in, const int* in_sizes, int n_in,
                              void* d_out, int out_size, void* d_ws, size_t ws_size,
                              hipStream_t stream) {
  const float* A = (const float*)d_in[0];
  const float* B = (const float*)d_in[1];
  char* ws = (char*)d_ws;
  const size_t fp8Bytes = (size_t)N_ROWS * KDIM;   // 8 MiB each
  uint8_t* Ah8 = (uint8_t*)ws;
  uint8_t* Bh8 = (uint8_t*)(ws + fp8Bytes);
  float* sq1 = (float*)(ws + 2 * fp8Bytes);
  float* sq2 = sq1 + N_ROWS;
  float* ws_min = sq2 + M_ROWS;
  float* part = ws_min + (size_t)NCHUNK * N_ROWS;

  conv_kernel<<<dim3((N_ROWS + M_ROWS) / 16), dim3(1024), 0, stream>>>(A, B, Ah8, Bh8, sq1, sq2);
  gemm_min_kernel<<<dim3((N_ROWS / BM) * NCHUNK), dim3(64), 0, stream>>>(Ah8, Bh8, sq2, ws_min);
  partial_kernel<<<dim3(64), dim3(256), 0, stream>>>(ws_min, sq1, part);
  final_kernel<<<dim3(1), dim3(64), 0, stream>>>(part, (float*)d_out);
}

// Round 9
// 316.697 us; speedup vs baseline: 1.0442x; 1.0442x over previous
//
#include <hip/hip_runtime.h>
#include <stdint.h>

#define N_ROWS 16384
#define M_ROWS 16384
#define KDIM   512
#define RW 128           // rows per wave (= per block; 1-wave blocks)
#define CT 2             // 16-col tiles per bt iteration (32 cols)
#define NCHUNK 8
#define CHUNK_ROWS (M_ROWS / NCHUNK)        // 2048
#define BT_PER_CHUNK (CHUNK_ROWS / (16*CT)) // 64
#define TILE_BYTES 8192  // one 16-row tile, all K: 16*512 fp8, shuffled

typedef int intx4 __attribute__((ext_vector_type(4)));
typedef int intx8 __attribute__((ext_vector_type(8)));
typedef float floatx4 __attribute__((ext_vector_type(4)));

#define UNIT_SCALE 0x7F7F7F7F  // E8M0 exp 127 -> 2^0 in every byte

// Kernel 1: fp32 -> fp8 e4m3, written in MFMA-FRAGMENT ORDER, + row norms.
// Shuffled layout, per 16-row tile t and phase p (2 KB at (t*4+p)*2048):
//   byte range [0,1024):   lane l = kg*16+fr -> rows t*16+fr, k=p*128+kg*32+[0,16)
//   byte range [1024,2048): same lanes, k += 16
// so a GEMM wave load at (base + lane*16) is a contiguous coalesced 1 KB.
// One wave per row; lane holds 8 floats (k0 = lane*8), whose 8 fp8 bytes all
// land in one aligned 8B granule: p=lane>>4, kg=(lane>>2)&3, h=(lane>>1)&1,
// b0=(lane&1)*8.
__global__ void __launch_bounds__(1024)
conv_kernel(const float* __restrict__ A, const float* __restrict__ B,
            uint8_t* __restrict__ As, uint8_t* __restrict__ Bs,
            float* __restrict__ sq1, float* __restrict__ sq2) {
  const int lane = threadIdx.x & 63;
  const int wv = threadIdx.x >> 6;
  int row = blockIdx.x * 16 + wv;
  const float* src;
  uint8_t* dstbase;
  float* sq;
  int r;
  if (row < N_ROWS) {
    r = row;
    src = A + (size_t)r * KDIM;
    dstbase = As;
    sq = sq1 + r;
  } else {
    r = row - N_ROWS;
    src = B + (size_t)r * KDIM;
    dstbase = Bs;
    sq = sq2 + r;
  }
  const float4* s4 = (const float4*)src;
  float4 v0 = s4[lane * 2];
  float4 v1 = s4[lane * 2 + 1];
  uint32_t w0 = 0, w1 = 0;
  w0 = __builtin_amdgcn_cvt_pk_fp8_f32(v0.x, v0.y, w0, 0);
  w0 = __builtin_amdgcn_cvt_pk_fp8_f32(v0.z, v0.w, w0, 1);
  w1 = __builtin_amdgcn_cvt_pk_fp8_f32(v1.x, v1.y, w1, 0);
  w1 = __builtin_amdgcn_cvt_pk_fp8_f32(v1.z, v1.w, w1, 1);
  uint2 pk = {w0, w1};
  const int tile = r >> 4, fr = r & 15;
  const int p = lane >> 4, kg = (lane >> 2) & 3, h = (lane >> 1) & 1,
            b0 = (lane & 1) * 8;
  *(uint2*)(dstbase + (size_t)tile * TILE_BYTES + p * 2048 + h * 1024 +
            (kg * 16 + fr) * 16 + b0) = pk;
  float s = v0.x * v0.x + v0.y * v0.y + v0.z * v0.z + v0.w * v0.w
          + v1.x * v1.x + v1.y * v1.y + v1.z * v1.z + v1.w * v1.w;
  #pragma unroll
  for (int off = 32; off; off >>= 1) s += __shfl_down(s, off, 64);
  if (lane == 0) *sq = s;
}

// Kernel 2: fused fp8 GEMM + running-min — NO LDS, NO BARRIERS.
// R8 failed because direct B loads were scattered (16 half-used lines/instr);
// with frag-order pre-shuffle every load is a contiguous per-wave 1 KB from
// the XCD-pinned L2-resident chunk. 128 rows/wave in registers (areg[8][4]
// intx8 = 256 VGPRs), acc[8][2]+runmin on top -> ~400 regs, 1 wave/SIMD.
// L2 demand = 4 waves/CU x 1 MB / 141k cyc = 30 B/cyc << 56 ceiling;
// MFMA floor 59 us with a pure VMEM-vmcnt pipeline (no barrier drains).
__global__ void __launch_bounds__(64, 1)
gemm_min_kernel(const uint8_t* __restrict__ As, const uint8_t* __restrict__ Bs,
                const float* __restrict__ sq2, float* __restrict__ ws_min) {
  const int lane = threadIdx.x;  // 0..63
  const int fr = lane & 15;
  const int kg = lane >> 4;      // 0..3

  const int bid = blockIdx.x;
  const int chunk = bid & 7;     // == XCD under bid%8 round-robin
  const int rowBase = (bid >> 3) * RW;
  const int colBase0 = chunk * CHUNK_ROWS;

  // ---- Persistent A fragments: coalesced loads from the shuffled layout.
  // areg[i][p] = rows rowBase+i*16.., k phase p (this lane's frag).
  intx8 areg[8][4];
  {
    const uint8_t* abase = As + (size_t)(rowBase >> 4) * TILE_BYTES + lane * 16;
    #pragma unroll
    for (int i = 0; i < 8; i++)
      #pragma unroll
      for (int p = 0; p < 4; p++) {
        const uint8_t* ap = abase + (size_t)i * TILE_BYTES + p * 2048;
        intx4 lo = *(const intx4*)ap;
        intx4 hi = *(const intx4*)(ap + 1024);
        areg[i][p] = __builtin_shufflevector(lo, hi, 0, 1, 2, 3, 4, 5, 6, 7);
      }
  }

  float runmin[8][4];
  #pragma unroll
  for (int i = 0; i < 8; i++)
    #pragma unroll
    for (int r4 = 0; r4 < 4; r4++) runmin[i][r4] = 3.0e38f;

  const uint8_t* bchunk = Bs + (size_t)(colBase0 >> 4) * TILE_BYTES + lane * 16;

  for (int bt = 0; bt < BT_PER_CHUNK; ++bt) {
    floatx4 acc[8][CT];
    #pragma unroll
    for (int i = 0; i < 8; i++)
      #pragma unroll
      for (int j = 0; j < CT; j++) acc[i][j] = (floatx4){0.f, 0.f, 0.f, 0.f};

    #pragma unroll
    for (int p = 0; p < 4; ++p) {
      #pragma unroll
      for (int j = 0; j < CT; j++) {
        const uint8_t* bp = bchunk + (size_t)(bt * CT + j) * TILE_BYTES + p * 2048;
        intx4 lo = *(const intx4*)bp;           // contiguous 1 KB per wave
        intx4 hi = *(const intx4*)(bp + 1024);  // contiguous 1 KB per wave
        intx8 bv = __builtin_shufflevector(lo, hi, 0, 1, 2, 3, 4, 5, 6, 7);
        #pragma unroll
        for (int i = 0; i < 8; i++)
          acc[i][j] = __builtin_amdgcn_mfma_scale_f32_16x16x128_f8f6f4(
              areg[i][p], bv, acc[i][j], 0, 0,
              0, UNIT_SCALE, 0, UNIT_SCALE);
      }
    }

    // Epilogue: cand = sq2[col] - 2*inner -> per-row running min.
    // C frag: col = tile*16 + fr, row = rowBase + i*16 + kg*4 + r4.
    #pragma unroll
    for (int j = 0; j < CT; j++) {
      const float s2 = sq2[colBase0 + (bt * CT + j) * 16 + fr];
      #pragma unroll
      for (int i = 0; i < 8; i++)
        #pragma unroll
        for (int r4 = 0; r4 < 4; r4++) {
          const float cand = fmaf(-2.f, acc[i][j][r4], s2);
          runmin[i][r4] = fminf(runmin[i][r4], cand);
        }
    }
  }

  // Min over the 16 cols per lane row-group: butterfly on lane bits 0..3.
  #pragma unroll
  for (int i = 0; i < 8; i++)
    #pragma unroll
    for (int r4 = 0; r4 < 4; r4++) {
      float v = runmin[i][r4];
      v = fminf(v, __shfl_xor(v, 1, 64));
      v = fminf(v, __shfl_xor(v, 2, 64));
      v = fminf(v, __shfl_xor(v, 4, 64));
      v = fminf(v, __shfl_xor(v, 8, 64));
      runmin[i][r4] = v;
    }

  if (fr == 0) {
    #pragma unroll
    for (int i = 0; i < 8; i++)
      #pragma unroll
      for (int r4 = 0; r4 < 4; r4++) {
        const int lrow = i * 16 + kg * 4 + r4;
        ws_min[(size_t)chunk * N_ROWS + rowBase + lrow] = runmin[i][r4];
      }
  }
}

// Kernel 3: per-row min across chunks + sqrt/relu + atomic mean accumulate.
// d_out is zeroed by a memsetAsync in kernel_launch before this runs.
__global__ void partial_kernel(const float* __restrict__ ws_min,
                               const float* __restrict__ sq1,
                               float* __restrict__ out) {
  const int r = blockIdx.x * 256 + threadIdx.x;
  float m = ws_min[r];
  #pragma unroll
  for (int c = 1; c < NCHUNK; c++) m = fminf(m, ws_min[(size_t)c * N_ROWS + r]);
  float d2 = sq1[r] + m;
  d2 = d2 > 0.f ? d2 : 0.f;
  float v = sqrtf(d2) - 0.1f;
  float s = v > 0.f ? v : 0.f;
  #pragma unroll
  for (int off = 32; off; off >>= 1) s += __shfl_down(s, off, 64);
  __shared__ float ps[4];
  if ((threadIdx.x & 63) == 0) ps[threadIdx.x >> 6] = s;
  __syncthreads();
  if (threadIdx.x == 0)
    atomicAdd(out, (ps[0] + ps[1] + ps[2] + ps[3]) * (1.0f / (float)N_ROWS));
}

extern "C" void kernel_launch(void* const* d_in, const int* in_sizes, int n_in,
                              void* d_out, int out_size, void* d_ws, size_t ws_size,
                              hipStream_t stream) {
  const float* A = (const float*)d_in[0];
  const float* B = (const float*)d_in[1];
  char* ws = (char*)d_ws;
  const size_t fp8Bytes = (size_t)N_ROWS * KDIM;   // 8 MiB each
  uint8_t* As = (uint8_t*)ws;
  uint8_t* Bs = (uint8_t*)(ws + fp8Bytes);
  float* sq1 = (float*)(ws + 2 * fp8Bytes);
  float* sq2 = sq1 + N_ROWS;
  float* ws_min = sq2 + M_ROWS;

  hipMemsetAsync(d_out, 0, sizeof(float), stream);
  conv_kernel<<<dim3((N_ROWS + M_ROWS) / 16), dim3(1024), 0, stream>>>(A, B, As, Bs, sq1, sq2);
  gemm_min_kernel<<<dim3((N_ROWS / RW) * NCHUNK), dim3(64), 0, stream>>>(As, Bs, sq2, ws_min);
  partial_kernel<<<dim3(64), dim3(256), 0, stream>>>(ws_min, sq1, (float*)d_out);
}

// Round 10
// 252.523 us; speedup vs baseline: 1.3095x; 1.2541x over previous
//
#include <hip/hip_runtime.h>
#include <stdint.h>

#define N_ROWS 16384
#define M_ROWS 16384
#define KDIM   512
#define RW 64            // rows per wave (register-persistent A: 128 VGPRs)
#define BLOCK_ROWS 128   // 2 waves/block
#define CT 2             // 16-col tiles per bt iteration (32 cols)
#define NCHUNK 8
#define CHUNK_ROWS (M_ROWS / NCHUNK)        // 2048
#define BT_PER_CHUNK (CHUNK_ROWS / (16*CT)) // 64
#define TILE_BYTES 8192  // one 16-row tile, all K: 16*512 fp8, frag-shuffled

typedef int intx4 __attribute__((ext_vector_type(4)));
typedef int intx8 __attribute__((ext_vector_type(8)));
typedef float floatx4 __attribute__((ext_vector_type(4)));

#define UNIT_SCALE 0x7F7F7F7F  // E8M0 exp 127 -> 2^0 in every byte

// Kernel 1: fp32 -> fp8 e4m3, written in MFMA-FRAGMENT ORDER, + row norms.
// Per 16-row tile t, phase p (2 KB at t*8192 + p*2048):
//   [0,1024):    lane l = kg*16+fr -> row t*16+fr, k = p*128+kg*32+[0,16)
//   [1024,2048): same lanes, k += 16
// so a GEMM wave load at (base + lane*16) is one contiguous coalesced 1 KB.
__global__ void __launch_bounds__(1024)
conv_kernel(const float* __restrict__ A, const float* __restrict__ B,
            uint8_t* __restrict__ As, uint8_t* __restrict__ Bs,
            float* __restrict__ sq1, float* __restrict__ sq2) {
  const int lane = threadIdx.x & 63;
  const int wv = threadIdx.x >> 6;
  int row = blockIdx.x * 16 + wv;
  const float* src;
  uint8_t* dstbase;
  float* sq;
  int r;
  if (row < N_ROWS) {
    r = row;
    src = A + (size_t)r * KDIM;
    dstbase = As;
    sq = sq1 + r;
  } else {
    r = row - N_ROWS;
    src = B + (size_t)r * KDIM;
    dstbase = Bs;
    sq = sq2 + r;
  }
  const float4* s4 = (const float4*)src;
  float4 v0 = s4[lane * 2];
  float4 v1 = s4[lane * 2 + 1];
  uint32_t w0 = 0, w1 = 0;
  w0 = __builtin_amdgcn_cvt_pk_fp8_f32(v0.x, v0.y, w0, 0);
  w0 = __builtin_amdgcn_cvt_pk_fp8_f32(v0.z, v0.w, w0, 1);
  w1 = __builtin_amdgcn_cvt_pk_fp8_f32(v1.x, v1.y, w1, 0);
  w1 = __builtin_amdgcn_cvt_pk_fp8_f32(v1.z, v1.w, w1, 1);
  uint2 pk = {w0, w1};
  const int tile = r >> 4, fr = r & 15;
  const int p = lane >> 4, kg = (lane >> 2) & 3, h = (lane >> 1) & 1,
            b0 = (lane & 1) * 8;
  *(uint2*)(dstbase + (size_t)tile * TILE_BYTES + p * 2048 + h * 1024 +
            (kg * 16 + fr) * 16 + b0) = pk;
  float s = v0.x * v0.x + v0.y * v0.y + v0.z * v0.z + v0.w * v0.w
          + v1.x * v1.x + v1.y * v1.y + v1.z * v1.z + v1.w * v1.w;
  #pragma unroll
  for (int off = 32; off; off >>= 1) s += __shfl_down(s, off, 64);
  if (lane == 0) *sq = s;
}

// Kernel 2: fused fp8 GEMM + running-min — NO LDS, NO BARRIERS, 2-wave blocks.
// R8 lesson: direct B loads must be coalesced -> frag-order layout (R9).
// R9 lesson: areg caps at 64 rows/wave (128 VGPRs) and 1 wave/SIMD can't
// hide latency -> 2 waves/SIMD here. Both waves of a block stream the SAME
// B addresses: wave 1 hits L1 behind wave 0 (bt window 16 KB << 32 KB L1),
// halving L2 demand to ~30 B/cyc vs the ~56 ceiling. K-loop is pure
// MFMA<->VMEM with compiler vmcnt pipelining — no barrier drains.
// chunk = bid & 7 pins each 1 MB fp8 B-chunk to one XCD's L2.
__global__ void __launch_bounds__(128, 2)
gemm_min_kernel(const uint8_t* __restrict__ As, const uint8_t* __restrict__ Bs,
                const float* __restrict__ sq2, float* __restrict__ ws_min) {
  const int lane = threadIdx.x & 63;
  const int wv = threadIdx.x >> 6;   // 0..1
  const int fr = lane & 15;
  const int kg = lane >> 4;          // 0..3

  const int bid = blockIdx.x;
  const int chunk = bid & 7;         // == XCD under bid%8 round-robin
  const int rowBase = (bid >> 3) * BLOCK_ROWS + wv * RW;
  const int colBase0 = chunk * CHUNK_ROWS;

  // ---- Persistent A fragments (coalesced from shuffled layout):
  // areg[i][p] = rows rowBase+i*16.., phase p. 4x4 intx8 = 128 VGPRs.
  intx8 areg[4][4];
  {
    const uint8_t* abase = As + (size_t)(rowBase >> 4) * TILE_BYTES + lane * 16;
    #pragma unroll
    for (int i = 0; i < 4; i++)
      #pragma unroll
      for (int p = 0; p < 4; p++) {
        const uint8_t* ap = abase + (size_t)i * TILE_BYTES + p * 2048;
        intx4 lo = *(const intx4*)ap;
        intx4 hi = *(const intx4*)(ap + 1024);
        areg[i][p] = __builtin_shufflevector(lo, hi, 0, 1, 2, 3, 4, 5, 6, 7);
      }
  }

  float runmin[4][4];
  #pragma unroll
  for (int i = 0; i < 4; i++)
    #pragma unroll
    for (int r4 = 0; r4 < 4; r4++) runmin[i][r4] = 3.0e38f;

  const uint8_t* bchunk = Bs + (size_t)(colBase0 >> 4) * TILE_BYTES + lane * 16;

  for (int bt = 0; bt < BT_PER_CHUNK; ++bt) {
    floatx4 acc[4][CT];
    #pragma unroll
    for (int i = 0; i < 4; i++)
      #pragma unroll
      for (int j = 0; j < CT; j++) acc[i][j] = (floatx4){0.f, 0.f, 0.f, 0.f};

    #pragma unroll
    for (int p = 0; p < 4; ++p) {
      #pragma unroll
      for (int j = 0; j < CT; j++) {
        const uint8_t* bp = bchunk + (size_t)(bt * CT + j) * TILE_BYTES + p * 2048;
        intx4 lo = *(const intx4*)bp;           // contiguous 1 KB per wave
        intx4 hi = *(const intx4*)(bp + 1024);
        intx8 bv = __builtin_shufflevector(lo, hi, 0, 1, 2, 3, 4, 5, 6, 7);
        #pragma unroll
        for (int i = 0; i < 4; i++)
          acc[i][j] = __builtin_amdgcn_mfma_scale_f32_16x16x128_f8f6f4(
              areg[i][p], bv, acc[i][j], 0, 0,
              0, UNIT_SCALE, 0, UNIT_SCALE);
      }
    }

    // Epilogue: cand = sq2[col] - 2*inner -> per-row running min.
    // C frag: col = (bt*CT+j)*16 + fr, row = rowBase + i*16 + kg*4 + r4.
    #pragma unroll
    for (int j = 0; j < CT; j++) {
      const float s2 = sq2[colBase0 + (bt * CT + j) * 16 + fr];
      #pragma unroll
      for (int i = 0; i < 4; i++)
        #pragma unroll
        for (int r4 = 0; r4 < 4; r4++) {
          const float cand = fmaf(-2.f, acc[i][j][r4], s2);
          runmin[i][r4] = fminf(runmin[i][r4], cand);
        }
    }
  }

  // Min over the 16 cols per lane row-group: butterfly on lane bits 0..3.
  #pragma unroll
  for (int i = 0; i < 4; i++)
    #pragma unroll
    for (int r4 = 0; r4 < 4; r4++) {
      float v = runmin[i][r4];
      v = fminf(v, __shfl_xor(v, 1, 64));
      v = fminf(v, __shfl_xor(v, 2, 64));
      v = fminf(v, __shfl_xor(v, 4, 64));
      v = fminf(v, __shfl_xor(v, 8, 64));
      runmin[i][r4] = v;
    }

  if (fr == 0) {
    #pragma unroll
    for (int i = 0; i < 4; i++)
      #pragma unroll
      for (int r4 = 0; r4 < 4; r4++) {
        const int lrow = i * 16 + kg * 4 + r4;
        ws_min[(size_t)chunk * N_ROWS + rowBase + lrow] = runmin[i][r4];
      }
  }
}

// Kernel 3: per-row min across chunks + sqrt/relu + atomic mean accumulate.
// d_out is zeroed by hipMemsetAsync in kernel_launch before this runs.
__global__ void partial_kernel(const float* __restrict__ ws_min,
                               const float* __restrict__ sq1,
                               float* __restrict__ out) {
  const int r = blockIdx.x * 256 + threadIdx.x;
  float m = ws_min[r];
  #pragma unroll
  for (int c = 1; c < NCHUNK; c++) m = fminf(m, ws_min[(size_t)c * N_ROWS + r]);
  float d2 = sq1[r] + m;
  d2 = d2 > 0.f ? d2 : 0.f;
  float v = sqrtf(d2) - 0.1f;
  float s = v > 0.f ? v : 0.f;
  #pragma unroll
  for (int off = 32; off; off >>= 1) s += __shfl_down(s, off, 64);
  __shared__ float ps[4];
  if ((threadIdx.x & 63) == 0) ps[threadIdx.x >> 6] = s;
  __syncthreads();
  if (threadIdx.x == 0)
    atomicAdd(out, (ps[0] + ps[1] + ps[2] + ps[3]) * (1.0f / (float)N_ROWS));
}

extern "C" void kernel_launch(void* const* d_in, const int* in_sizes, int n_in,
                              void* d_out, int out_size, void* d_ws, size_t ws_size,
                              hipStream_t stream) {
  const float* A = (const float*)d_in[0];
  const float* B = (const float*)d_in[1];
  char* ws = (char*)d_ws;
  const size_t fp8Bytes = (size_t)N_ROWS * KDIM;   // 8 MiB each
  uint8_t* As = (uint8_t*)ws;
  uint8_t* Bs = (uint8_t*)(ws + fp8Bytes);
  float* sq1 = (float*)(ws + 2 * fp8Bytes);
  float* sq2 = sq1 + N_ROWS;
  float* ws_min = sq2 + M_ROWS;

  hipMemsetAsync(d_out, 0, sizeof(float), stream);
  conv_kernel<<<dim3((N_ROWS + M_ROWS) / 16), dim3(1024), 0, stream>>>(A, B, As, Bs, sq1, sq2);
  gemm_min_kernel<<<dim3((N_ROWS / BLOCK_ROWS) * NCHUNK), dim3(128), 0, stream>>>(As, Bs, sq2, ws_min);
  partial_kernel<<<dim3(64), dim3(256), 0, stream>>>(ws_min, sq1, (float*)d_out);
}